// Round 7
// baseline (1678.921 us; speedup 1.0000x reference)
//
#include <hip/hip_runtime.h>

typedef short bf16x8 __attribute__((ext_vector_type(8)));
typedef float f32x4  __attribute__((ext_vector_type(4)));

// Problem constants
#define NB   64
#define NT   256
#define NC   512
#define NK   1024
#define NQ   6
#define NROWS (NB*NT)        // 16384
#define QOUT_ELEMS 8388608   // B*C*T
#define IDX_ELEMS  98304     // B*T*Q
#define DELTA 0.5f           // candidate window (~10x the 512-term bf16 approx error std)

// ws layout (bytes)
#define WS_CAND   0                        // u32[16384*32] = 2 MiB
#define WS_CCNT   0x200000                 // u32[16384]
#define WS_COUNTS 0x220000                 // u32[1024]
#define WS_CSUM   0x221000                 // f32[6]
#define WS_CMEAN  0x221020                 // f32[6]
#define WS_PERP   0x221040                 // f32[6]
#define WS_DONE   0x221060                 // u32[1]
#define WS_CBN    0x222000                 // f32[6144]
#define WS_XHI    0x230000                 // ushort[16384*512], 16 MiB
#define WS_CBHI   (WS_XHI + 16777216)      // ushort[6144*512], 6 MiB

// bf16 helpers (RNE; data is gaussian, no inf/nan)
__device__ __forceinline__ unsigned short f2bf(float f) {
    unsigned u = __float_as_uint(f);
    return (unsigned short)((u + 0x7FFFu + ((u >> 16) & 1u)) >> 16);
}

// -------- codebook conversion (all 6 layers) + half-norms --------
__global__ __launch_bounds__(256) void vq_cvt_cb(const float* __restrict__ cb,
                                                 unsigned short* __restrict__ cbhi,
                                                 float* __restrict__ cbn) {
    int lane = threadIdx.x & 63, wid = threadIdx.x >> 6;
    int code = blockIdx.x * 4 + wid;                 // 0..6143
    const float* row = cb + (size_t)code * NC;
    float4 v0 = *(const float4*)(row + lane * 8);
    float4 v1 = *(const float4*)(row + lane * 8 + 4);
    float vs[8] = {v0.x, v0.y, v0.z, v0.w, v1.x, v1.y, v1.z, v1.w};
    ushort4 a, b;
    unsigned short* ap = &a.x; unsigned short* bp = &b.x;
    float s = 0.f;
    #pragma unroll
    for (int j = 0; j < 4; ++j) {
        s += vs[j] * vs[j] + vs[j+4] * vs[j+4];
        ap[j] = f2bf(vs[j]); bp[j] = f2bf(vs[j+4]);
    }
    size_t o = (size_t)code * NC + lane * 8;
    *(ushort4*)(cbhi + o) = a; *(ushort4*)(cbhi + o + 4) = b;
    #pragma unroll
    for (int off = 32; off; off >>= 1) s += __shfl_down(s, off, 64);
    if (lane == 0) cbn[code] = 0.5f * s;
}

// -------- x conversion: (B,C,T) fp32 -> (r=b*T+t, c) bf16; also zero flags ----
__global__ __launch_bounds__(256) void vq_cvt_x(const float* __restrict__ x,
                                                unsigned short* __restrict__ xh,
                                                unsigned int* __restrict__ candcnt,
                                                unsigned int* __restrict__ done) {
    __shared__ unsigned short hs[64][72];
    int bx = blockIdx.x;
    int b = bx >> 5, tt = (bx >> 3) & 3, c0 = (bx & 7) << 6;
    int t0 = tt << 6, tid = threadIdx.x;
    if ((bx & 7) == 0 && tid < 64) candcnt[b * 256 + t0 + tid] = 0u;  // layer-0 init
    if (bx == 0 && tid == 0) *done = 0u;
    const float* base = x + (size_t)b * (NC * NT) + t0;
    #pragma unroll
    for (int i = 0; i < 4; ++i) {
        int f = tid + (i << 8);
        int c_l = f >> 4, t4 = f & 15;
        float4 v = *(const float4*)(base + (size_t)(c0 + c_l) * NT + (t4 << 2));
        ushort4 hh;
        hh.x = f2bf(v.x); hh.y = f2bf(v.y); hh.z = f2bf(v.z); hh.w = f2bf(v.w);
        *(ushort4*)&hs[c_l][t4 << 2] = hh;
    }
    __syncthreads();
    int row0 = b * NT + t0;
    #pragma unroll
    for (int i = 0; i < 4; ++i) {
        int f = tid + (i << 8);
        int r_l = f >> 4, c4 = f & 15;
        ushort4 hh;
        hh.x = hs[c4*4+0][r_l]; hh.y = hs[c4*4+1][r_l];
        hh.z = hs[c4*4+2][r_l]; hh.w = hs[c4*4+3][r_l];
        *(ushort4*)(xh + (size_t)(row0 + r_l) * NC + c0 + (c4 << 2)) = hh;
    }
}

// -------- bf16 MFMA approx distance + candidate emission --------
// grid (128 rowblocks, 8 codegroups), 256 threads = 4 waves, 64x64 per wave.
// BK=64, XOR-swizzled LDS (conflict-free), REGISTER-PREFETCH staging so next
// chunk's global-load latency overlaps ds_read+MFMA of the current chunk.
__global__ __launch_bounds__(256) void vq_dist(
    const unsigned short* __restrict__ xh, const unsigned short* __restrict__ ch,
    const float* __restrict__ cbn,
    unsigned int* __restrict__ cand, unsigned int* __restrict__ candcnt,
    unsigned int* __restrict__ counts, float* __restrict__ commit_slot)
{
    const int rb = blockIdx.x, cg = blockIdx.y, tid = threadIdx.x;
    if (rb == 0 && cg == 0) {     // init for the fused kernel of this layer
        for (int i = tid; i < NK; i += 256) counts[i] = 0u;
        if (tid == 0) *commit_slot = 0.f;
    }
    __shared__ unsigned short smem[16384];   // A: [0,8192) 128 rows x 64, B: [8192,16384)
    const int wave = tid >> 6, lane = tid & 63;
    const int idx16 = lane & 15, quad = lane >> 4;
    const int wm = wave >> 1, wn = wave & 1;
    const int m0 = rb * 128, n0 = cg * 128;

    // staging map: waves 0,1 -> A (xh rows m0..), waves 2,3 -> B (ch rows n0..)
    const unsigned short* gsrc = (wave < 2) ? xh : ch;
    const int rbase = (wave < 2) ? m0 : n0;
    const int wseg  = (wave & 1) * 64;
    const int srow  = wseg + (lane >> 3);                 // +8 per staging instr
    const int sq    = (lane & 7) ^ ((lane >> 3) & 7);     // swizzled chunk
    const unsigned short* gp = gsrc + (size_t)(rbase + srow) * NC + sq * 8;
    unsigned short* lp = &smem[((wave >= 2) ? 8192 : 0) + wseg * 64 + lane * 8];

    uint4 pf[8];
    #pragma unroll
    for (int i = 0; i < 8; ++i)
        pf[i] = *(const uint4*)(gp + (size_t)(i * 8) * NC);

    f32x4 acc[4][4];
    #pragma unroll
    for (int a = 0; a < 4; ++a)
        #pragma unroll
        for (int c = 0; c < 4; ++c) acc[a][c] = (f32x4){0.f, 0.f, 0.f, 0.f};

    for (int cc = 0; cc < NC; cc += 64) {
        __syncthreads();
        #pragma unroll
        for (int i = 0; i < 8; ++i)
            *(uint4*)(lp + i * 512) = pf[i];
        __syncthreads();
        if (cc + 64 < NC) {
            #pragma unroll
            for (int i = 0; i < 8; ++i)
                pf[i] = *(const uint4*)(gp + (size_t)(i * 8) * NC + cc + 64);
        }
        #pragma unroll
        for (int ks = 0; ks < 2; ++ks) {
            bf16x8 a[4], b[4];
            #pragma unroll
            for (int mt = 0; mt < 4; ++mt) {
                int r = wm * 64 + mt * 16 + idx16;
                a[mt] = *(const bf16x8*)&smem[r * 64 + (((quad + 4*ks) ^ (r & 7)) << 3)];
            }
            #pragma unroll
            for (int nt = 0; nt < 4; ++nt) {
                int r = wn * 64 + nt * 16 + idx16;
                b[nt] = *(const bf16x8*)&smem[8192 + r * 64 + (((quad + 4*ks) ^ (r & 7)) << 3)];
            }
            #pragma unroll
            for (int mt = 0; mt < 4; ++mt)
                #pragma unroll
                for (int nt = 0; nt < 4; ++nt)
                    acc[mt][nt] = __builtin_amdgcn_mfma_f32_16x16x32_bf16(a[mt], b[nt], acc[mt][nt], 0, 0, 0);
        }
    }
    // epilogue: per-row wave-min over this wave's 64 codes, delta-window emission
    float cn[4]; int ng[4];
    #pragma unroll
    for (int nt = 0; nt < 4; ++nt) {
        ng[nt] = n0 + wn * 64 + nt * 16 + idx16;
        cn[nt] = cbn[ng[nt]];
    }
    #pragma unroll
    for (int mt = 0; mt < 4; ++mt) {
        #pragma unroll
        for (int r = 0; r < 4; ++r) {
            float sc[4];
            float m = 3.402823466e38f;
            #pragma unroll
            for (int nt = 0; nt < 4; ++nt) {
                sc[nt] = cn[nt] - acc[mt][nt][r];
                m = fminf(m, sc[nt]);
            }
            #pragma unroll
            for (int sft = 1; sft < 16; sft <<= 1)
                m = fminf(m, __shfl_xor(m, sft, 64));
            m += DELTA;
            const int row = m0 + wm * 64 + mt * 16 + quad * 4 + r;
            #pragma unroll
            for (int nt = 0; nt < 4; ++nt) {
                if (sc[nt] <= m) {
                    unsigned slot = atomicAdd(&candcnt[row], 1u);
                    if (slot < 32u) cand[(size_t)row * 32 + slot] = (unsigned)ng[nt];
                }
            }
        }
    }
}

// -------- FUSED: exact fp32 rescore + residual update + commit + stats --------
// grid 1024 blocks (16 rows each), 256 threads = 4 waves.
// Phase 1: stage src rows in LDS, exact-rescore candidates -> best per row.
// Phase 2: gather selected cb rows to LDS, RMW residual (or final qout at q=5),
//          commit sum, bf16 emit for next layer; last block computes stats.
__global__ __launch_bounds__(256) void vq_fuse(
    const float* __restrict__ src,     // residual (B,C,T) current layer input
    const float* __restrict__ x,       // original input (for q=5 final)
    float* __restrict__ dst,           // residual-out slot == qout output buffer
    const float* __restrict__ cb, const float* __restrict__ cbn,
    const unsigned int* __restrict__ cand, unsigned int* __restrict__ candcnt,
    float* __restrict__ out_idx,
    unsigned short* __restrict__ xh,
    unsigned int* __restrict__ counts,
    float* __restrict__ csum, float* __restrict__ cmean, float* __restrict__ perp,
    float* __restrict__ out_tail, unsigned int* __restrict__ done, int q)
{
    __shared__ float xl[16][516];       // src rows [t_local][c]
    __shared__ float cbs[16][516];      // selected codebook rows
    __shared__ int s_best[16];
    __shared__ float wred[4];
    __shared__ unsigned int lastflag;
    const int tid = threadIdx.x;
    const int b = blockIdx.x >> 4, t0 = (blockIdx.x & 15) << 4;
    const int row0 = b * NT + t0;
    const size_t gbase = (size_t)b * (NC * NT) + t0;
    const float* sbase = src + gbase;
    // stage src 16 rows (coalesced 64B segments along t)
    #pragma unroll
    for (int i = 0; i < 8; ++i) {
        int f = tid + (i << 8);
        int c = f >> 2, t4 = f & 3;
        float4 v = *(const float4*)(sbase + (size_t)c * NT + (t4 << 2));
        xl[(t4<<2)+0][c] = v.x; xl[(t4<<2)+1][c] = v.y;
        xl[(t4<<2)+2][c] = v.z; xl[(t4<<2)+3][c] = v.w;
    }
    __syncthreads();
    const int w = tid >> 6, lane = tid & 63;
    for (int rr = 0; rr < 4; ++rr) {
        const int tl = w * 4 + rr, row = row0 + tl;
        float4 xa = *(const float4*)&xl[tl][lane << 3];
        float4 xb = *(const float4*)&xl[tl][(lane << 3) + 4];
        int n = (int)candcnt[row]; if (n > 32) n = 32;
        float bs = 3.402823466e38f; int bi = 0x7FFFFFFF;
        for (int j = 0; j < n; ++j) {
            int code = (int)cand[(size_t)row * 32 + j];
            const float* cr = cb + (size_t)code * NC + (lane << 3);
            float4 ca = *(const float4*)cr;
            float4 cc = *(const float4*)(cr + 4);
            float s = xa.x*ca.x + xa.y*ca.y + xa.z*ca.z + xa.w*ca.w
                    + xb.x*cc.x + xb.y*cc.y + xb.z*cc.z + xb.w*cc.w;
            #pragma unroll
            for (int off = 1; off < 64; off <<= 1) s += __shfl_xor(s, off, 64);
            s = cbn[code] - s;
            if (s < bs || (s == bs && code < bi)) { bs = s; bi = code; }
        }
        if (lane == 0) {
            s_best[tl] = bi;
            out_idx[(size_t)row * NQ + q] = (float)bi;
            atomicAdd(&counts[bi], 1u);
        }
    }
    if (tid < 16) candcnt[row0 + tid] = 0u;   // reset for next layer's dist
    __syncthreads();
    // gather selected codebook rows (coalesced along c per row)
    #pragma unroll
    for (int i = 0; i < 8; ++i) {
        int f = tid + (i << 8);
        int r = f >> 7, c4 = f & 127;
        float4 v = *(const float4*)(cb + (size_t)s_best[r] * NC + (c4 << 2));
        *(float4*)&cbs[r][c4 << 2] = v;
    }
    __syncthreads();
    // RMW along t (+ q5 finalize) with commit accumulation
    float cs = 0.f;
    float* dbase = dst + gbase;
    const float* xbase = x + gbase;
    #pragma unroll
    for (int i = 0; i < 8; ++i) {
        int f = tid + (i << 8);
        int c = f >> 2, t4 = f & 3;
        float nv[4];
        #pragma unroll
        for (int j = 0; j < 4; ++j) {
            int t = (t4 << 2) + j;
            nv[j] = xl[t][c] - cbs[t][c];
            cs += nv[j] * nv[j];
        }
        size_t o = (size_t)c * NT + (t4 << 2);
        float4 ov;
        if (q == NQ - 1) {
            float4 xv = *(const float4*)(xbase + o);
            ov.x = xv.x - nv[0]; ov.y = xv.y - nv[1];
            ov.z = xv.z - nv[2]; ov.w = xv.w - nv[3];
        } else {
            ov.x = nv[0]; ov.y = nv[1]; ov.z = nv[2]; ov.w = nv[3];
        }
        *(float4*)(dbase + o) = ov;
    }
    // bf16 emit for next layer (skip at last layer)
    if (q != NQ - 1) {
        #pragma unroll
        for (int i = 0; i < 8; ++i) {
            int f = tid + (i << 8);
            int r = f >> 7, c4 = f & 127;
            ushort4 hh;
            hh.x = f2bf(xl[r][c4*4+0] - cbs[r][c4*4+0]);
            hh.y = f2bf(xl[r][c4*4+1] - cbs[r][c4*4+1]);
            hh.z = f2bf(xl[r][c4*4+2] - cbs[r][c4*4+2]);
            hh.w = f2bf(xl[r][c4*4+3] - cbs[r][c4*4+3]);
            *(ushort4*)(xh + (size_t)(row0 + r) * NC + (c4 << 2)) = hh;
        }
    }
    #pragma unroll
    for (int off = 32; off; off >>= 1) cs += __shfl_down(cs, off, 64);
    if ((tid & 63) == 0) wred[tid >> 6] = cs;
    __syncthreads();
    if (tid == 0) {
        atomicAdd(&csum[q], wred[0] + wred[1] + wred[2] + wred[3]);
        __threadfence();
        lastflag = atomicAdd(done, 1u);
    }
    __syncthreads();
    if (lastflag == 1023u) {                   // last block: fused per-layer stats
        float v = 0.f;
        for (int i = tid; i < NK; i += 256) {
            float p = (float)atomicAdd(&counts[i], 0u) * (1.f / (float)NROWS);
            v += p * logf(p + 1e-7f);
        }
        #pragma unroll
        for (int off = 32; off; off >>= 1) v += __shfl_down(v, off, 64);
        if ((tid & 63) == 0) wred[tid >> 6] = v;
        __syncthreads();
        if (tid == 0) {
            float S = wred[0] + wred[1] + wred[2] + wred[3];
            perp[q]  = expf(-S);
            cmean[q] = atomicAdd(&csum[q], 0.f) * (1.f / ((float)NROWS * (float)NC));
            if (q == NQ - 1) {
                float mc = 0.f, mp = 0.f;
                for (int i = 0; i < NQ; ++i) { mc += cmean[i]; mp += perp[i]; }
                out_tail[0] = mc / (float)NQ;
                out_tail[1] = mp / (float)NQ;
            }
            *done = 0u;                        // reset for next layer
        }
    }
}

extern "C" void kernel_launch(void* const* d_in, const int* in_sizes, int n_in,
                              void* d_out, int out_size, void* d_ws, size_t ws_size,
                              hipStream_t stream) {
    const float* x  = (const float*)d_in[0];
    const float* cb = (const float*)d_in[1];       // (Q,K,C)
    float* out      = (float*)d_out;
    float* res      = out;                          // residual lives in qout slot
    float* out_idx  = out + QOUT_ELEMS;
    float* out_tail = out + QOUT_ELEMS + IDX_ELEMS;
    char* ws = (char*)d_ws;
    unsigned int* cand    = (unsigned int*)(ws + WS_CAND);
    unsigned int* candcnt = (unsigned int*)(ws + WS_CCNT);
    unsigned int* counts  = (unsigned int*)(ws + WS_COUNTS);
    float* csum  = (float*)(ws + WS_CSUM);
    float* cmean = (float*)(ws + WS_CMEAN);
    float* perp  = (float*)(ws + WS_PERP);
    unsigned int* done = (unsigned int*)(ws + WS_DONE);
    float* cbn   = (float*)(ws + WS_CBN);
    unsigned short* xh   = (unsigned short*)(ws + WS_XHI);
    unsigned short* cbhi = (unsigned short*)(ws + WS_CBHI);

    vq_cvt_cb<<<1536, 256, 0, stream>>>(cb, cbhi, cbn);
    vq_cvt_x<<<2048, 256, 0, stream>>>(x, xh, candcnt, done);
    for (int q = 0; q < NQ; ++q) {
        const float* src = (q == 0) ? x : res;
        const float* cbq = cb + (size_t)q * NK * NC;
        vq_dist<<<dim3(128, 8), 256, 0, stream>>>(
            xh, cbhi + (size_t)q * NK * NC, cbn + q * NK,
            cand, candcnt, counts, csum + q);
        vq_fuse<<<1024, 256, 0, stream>>>(src, x, res, cbq, cbn + q * NK,
                                          cand, candcnt, out_idx, xh, counts,
                                          csum, cmean, perp, out_tail, done, q);
    }
}

// Round 8
// 999.397 us; speedup vs baseline: 1.6799x; 1.6799x over previous
//
#include <hip/hip_runtime.h>

typedef short bf16x8 __attribute__((ext_vector_type(8)));
typedef float f32x4  __attribute__((ext_vector_type(4)));

// Problem constants
#define NB   64
#define NT   256
#define NC   512
#define NK   1024
#define NQ   6
#define NROWS (NB*NT)        // 16384
#define QOUT_ELEMS 8388608   // B*C*T
#define IDX_ELEMS  98304     // B*T*Q
#define DELTA 0.5f           // candidate window (~10x the 512-term bf16 approx error std)

// ws layout (bytes)
#define WS_CAND   0                        // u32[16384*32] = 2 MiB
#define WS_CCNT   0x200000                 // u32[16384]
#define WS_BIDX   0x210000                 // i32[16384]
#define WS_COUNTS 0x220000                 // u32[1024]
#define WS_CSUM   0x221000                 // f32[6]
#define WS_CMEAN  0x221020                 // f32[6]
#define WS_PERP   0x221040                 // f32[6]
#define WS_DONE   0x221060                 // u32[1]
#define WS_CBN    0x222000                 // f32[6144]
#define WS_XHI    0x230000                 // ushort[16384*512], 16 MiB
#define WS_CBHI   (WS_XHI + 16777216)      // ushort[6144*512], 6 MiB

// bf16 helpers (RNE; data is gaussian, no inf/nan)
__device__ __forceinline__ unsigned short f2bf(float f) {
    unsigned u = __float_as_uint(f);
    return (unsigned short)((u + 0x7FFFu + ((u >> 16) & 1u)) >> 16);
}

__device__ __forceinline__ void load_lds16(const unsigned short* g, unsigned short* l) {
    __builtin_amdgcn_global_load_lds(
        (const __attribute__((address_space(1))) unsigned int*)g,
        (__attribute__((address_space(3))) unsigned int*)l,
        16, 0, 0);
}

// -------- codebook conversion (all 6 layers) + half-norms --------
__global__ __launch_bounds__(256) void vq_cvt_cb(const float* __restrict__ cb,
                                                 unsigned short* __restrict__ cbhi,
                                                 float* __restrict__ cbn) {
    int lane = threadIdx.x & 63, wid = threadIdx.x >> 6;
    int code = blockIdx.x * 4 + wid;                 // 0..6143
    const float* row = cb + (size_t)code * NC;
    float4 v0 = *(const float4*)(row + lane * 8);
    float4 v1 = *(const float4*)(row + lane * 8 + 4);
    float vs[8] = {v0.x, v0.y, v0.z, v0.w, v1.x, v1.y, v1.z, v1.w};
    ushort4 a, b;
    unsigned short* ap = &a.x; unsigned short* bp = &b.x;
    float s = 0.f;
    #pragma unroll
    for (int j = 0; j < 4; ++j) {
        s += vs[j] * vs[j] + vs[j+4] * vs[j+4];
        ap[j] = f2bf(vs[j]); bp[j] = f2bf(vs[j+4]);
    }
    size_t o = (size_t)code * NC + lane * 8;
    *(ushort4*)(cbhi + o) = a; *(ushort4*)(cbhi + o + 4) = b;
    #pragma unroll
    for (int off = 32; off; off >>= 1) s += __shfl_down(s, off, 64);
    if (lane == 0) cbn[code] = 0.5f * s;
}

// -------- x conversion: (B,C,T) fp32 -> (r=b*T+t, c) bf16; also zero flags ----
__global__ __launch_bounds__(256) void vq_cvt_x(const float* __restrict__ x,
                                                unsigned short* __restrict__ xh,
                                                unsigned int* __restrict__ candcnt,
                                                unsigned int* __restrict__ done) {
    __shared__ unsigned short hs[64][72];
    int bx = blockIdx.x;
    int b = bx >> 5, tt = (bx >> 3) & 3, c0 = (bx & 7) << 6;
    int t0 = tt << 6, tid = threadIdx.x;
    if ((bx & 7) == 0 && tid < 64) candcnt[b * 256 + t0 + tid] = 0u;  // layer-0 init
    if (bx == 0 && tid == 0) *done = 0u;
    const float* base = x + (size_t)b * (NC * NT) + t0;
    #pragma unroll
    for (int i = 0; i < 4; ++i) {
        int f = tid + (i << 8);
        int c_l = f >> 4, t4 = f & 15;
        float4 v = *(const float4*)(base + (size_t)(c0 + c_l) * NT + (t4 << 2));
        ushort4 hh;
        hh.x = f2bf(v.x); hh.y = f2bf(v.y); hh.z = f2bf(v.z); hh.w = f2bf(v.w);
        *(ushort4*)&hs[c_l][t4 << 2] = hh;
    }
    __syncthreads();
    int row0 = b * NT + t0;
    #pragma unroll
    for (int i = 0; i < 4; ++i) {
        int f = tid + (i << 8);
        int r_l = f >> 4, c4 = f & 15;
        ushort4 hh;
        hh.x = hs[c4*4+0][r_l]; hh.y = hs[c4*4+1][r_l];
        hh.z = hs[c4*4+2][r_l]; hh.w = hs[c4*4+3][r_l];
        *(ushort4*)(xh + (size_t)(row0 + r_l) * NC + c0 + (c4 << 2)) = hh;
    }
}

// -------- bf16 MFMA approx distance + candidate emission --------
// grid (128 rowblocks, 4 codegroups), 256 threads = 4 waves.
// Tile 128 rows x 256 codes; per wave 64 rows x 128 codes (acc 4x8).
// BK=64, XOR-swizzled LDS (conflict-free), global_load_lds width-16 staging
// (round-7 lesson: register-prefetch staging regressed; keep direct-to-LDS).
__global__ __launch_bounds__(256) void vq_dist(
    const unsigned short* __restrict__ xh, const unsigned short* __restrict__ ch,
    const float* __restrict__ cbn,
    unsigned int* __restrict__ cand, unsigned int* __restrict__ candcnt,
    unsigned int* __restrict__ counts, float* __restrict__ commit_slot)
{
    const int rb = blockIdx.x, cg = blockIdx.y, tid = threadIdx.x;
    if (rb == 0 && cg == 0) {     // init for rescore/update of this layer
        for (int i = tid; i < NK; i += 256) counts[i] = 0u;
        if (tid == 0) *commit_slot = 0.f;
    }
    __shared__ unsigned short smem[24576];   // A: [0,8192) 128x64; B: [8192,24576) 256x64
    const int wave = tid >> 6, lane = tid & 63;
    const int idx16 = lane & 15, quad = lane >> 4;
    const int wm = wave >> 1, wn = wave & 1;
    const int m0 = rb * 128, n0 = cg * 256;

    // staging: thread handles A rows tid>>3 (+32/i, 4 instrs) and B rows (+32/i, 8 instrs)
    const int srow = tid >> 3, sslot = tid & 7;
    const unsigned short* gpa = xh + (size_t)(m0 + srow) * NC + ((sslot ^ (srow & 7)) << 3);
    const unsigned short* gpb = ch + (size_t)(n0 + srow) * NC + ((sslot ^ (srow & 7)) << 3);
    unsigned short* lpa = &smem[tid * 8];
    unsigned short* lpb = &smem[8192 + tid * 8];

    f32x4 acc[4][8];
    #pragma unroll
    for (int a = 0; a < 4; ++a)
        #pragma unroll
        for (int c = 0; c < 8; ++c) acc[a][c] = (f32x4){0.f, 0.f, 0.f, 0.f};

    for (int cc = 0; cc < NC; cc += 64) {
        __syncthreads();
        #pragma unroll
        for (int i = 0; i < 4; ++i)
            load_lds16(gpa + (size_t)(i * 32) * NC + cc, lpa + i * 2048);
        #pragma unroll
        for (int i = 0; i < 8; ++i)
            load_lds16(gpb + (size_t)(i * 32) * NC + cc, lpb + i * 2048);
        __syncthreads();
        #pragma unroll
        for (int ks = 0; ks < 2; ++ks) {
            bf16x8 a[4], b[8];
            #pragma unroll
            for (int mt = 0; mt < 4; ++mt) {
                int r = wm * 64 + mt * 16 + idx16;
                a[mt] = *(const bf16x8*)&smem[r * 64 + (((quad + 4*ks) ^ (r & 7)) << 3)];
            }
            #pragma unroll
            for (int nt = 0; nt < 8; ++nt) {
                int r = wn * 128 + nt * 16 + idx16;
                b[nt] = *(const bf16x8*)&smem[8192 + r * 64 + (((quad + 4*ks) ^ (r & 7)) << 3)];
            }
            #pragma unroll
            for (int mt = 0; mt < 4; ++mt)
                #pragma unroll
                for (int nt = 0; nt < 8; ++nt)
                    acc[mt][nt] = __builtin_amdgcn_mfma_f32_16x16x32_bf16(a[mt], b[nt], acc[mt][nt], 0, 0, 0);
        }
    }
    // epilogue: per-row wave-min over this wave's 128 codes, delta-window emission
    float cn[8]; int ng[8];
    #pragma unroll
    for (int nt = 0; nt < 8; ++nt) {
        ng[nt] = n0 + wn * 128 + nt * 16 + idx16;
        cn[nt] = cbn[ng[nt]];
    }
    #pragma unroll
    for (int mt = 0; mt < 4; ++mt) {
        #pragma unroll
        for (int r = 0; r < 4; ++r) {
            float sc[8];
            float m = 3.402823466e38f;
            #pragma unroll
            for (int nt = 0; nt < 8; ++nt) {
                sc[nt] = cn[nt] - acc[mt][nt][r];
                m = fminf(m, sc[nt]);
            }
            #pragma unroll
            for (int sft = 1; sft < 16; sft <<= 1)
                m = fminf(m, __shfl_xor(m, sft, 64));
            m += DELTA;
            const int row = m0 + wm * 64 + mt * 16 + quad * 4 + r;
            #pragma unroll
            for (int nt = 0; nt < 8; ++nt) {
                if (sc[nt] <= m) {
                    unsigned slot = atomicAdd(&candcnt[row], 1u);
                    if (slot < 32u) cand[(size_t)row * 32 + slot] = (unsigned)ng[nt];
                }
            }
        }
    }
}

// -------- exact fp32 rescore of candidates: final argmin + histogram --------
// grid 1024 blocks (16 rows each), 256 threads = 4 waves, 4 rows/wave.
__global__ __launch_bounds__(256) void vq_rescore(
    const float* __restrict__ src,     // residual (B,C,T) current layer input
    const float* __restrict__ cb, const float* __restrict__ cbn,
    const unsigned int* __restrict__ cand, const unsigned int* __restrict__ candcnt,
    int* __restrict__ best_idx, float* __restrict__ out_idx,
    unsigned int* __restrict__ counts, int q)
{
    __shared__ float xl[16][512];      // [t_local][c], 32 KiB
    const int tid = threadIdx.x;
    const int b = blockIdx.x >> 4, t0 = (blockIdx.x & 15) << 4;
    const float* base = src + (size_t)b * (NC * NT) + t0;
    #pragma unroll
    for (int i = 0; i < 8; ++i) {
        int f = tid + (i << 8);
        int c = f >> 2, t4 = f & 3;
        float4 v = *(const float4*)(base + (size_t)c * NT + (t4 << 2));
        xl[(t4 << 2) + 0][c] = v.x; xl[(t4 << 2) + 1][c] = v.y;
        xl[(t4 << 2) + 2][c] = v.z; xl[(t4 << 2) + 3][c] = v.w;
    }
    __syncthreads();
    const int w = tid >> 6, lane = tid & 63;
    const int row0 = b * NT + t0;
    for (int rr = 0; rr < 4; ++rr) {
        const int tl = w * 4 + rr;
        const int row = row0 + tl;
        float4 xa = *(const float4*)&xl[tl][lane << 3];
        float4 xb = *(const float4*)&xl[tl][(lane << 3) + 4];
        int n = (int)candcnt[row]; if (n > 32) n = 32;
        float bs = 3.402823466e38f; int bi = 0x7FFFFFFF;
        for (int j = 0; j < n; ++j) {
            int code = (int)cand[(size_t)row * 32 + j];
            const float* cr = cb + (size_t)code * NC + (lane << 3);
            float4 ca = *(const float4*)cr;
            float4 cc = *(const float4*)(cr + 4);
            float s = xa.x*ca.x + xa.y*ca.y + xa.z*ca.z + xa.w*ca.w
                    + xb.x*cc.x + xb.y*cc.y + xb.z*cc.z + xb.w*cc.w;
            #pragma unroll
            for (int off = 1; off < 64; off <<= 1) s += __shfl_xor(s, off, 64);
            s = cbn[code] - s;
            if (s < bs || (s == bs && code < bi)) { bs = s; bi = code; }
        }
        if (lane == 0) {
            best_idx[row] = bi;
            out_idx[(size_t)row * NQ + q] = (float)bi;
            atomicAdd(&counts[bi], 1u);
        }
    }
}

// -------- gather + residual update (or q5 qout) + commit + bf16 emit + stats ----
// grid 256 blocks (64 rows each), 256 threads; last block computes perp/cmean.
__global__ __launch_bounds__(256) void vq_update(
    const float* __restrict__ src,    // residual before (x for q=0), (B,C,T)
    const float* __restrict__ x,      // original input (for q=5 finalize)
    float* __restrict__ dst,          // residual after / qout at q=5
    const float* __restrict__ cb,
    const int* __restrict__ best_idx,
    unsigned short* __restrict__ xh,  // bf16 residual for next layer's dist
    unsigned int* __restrict__ candcnt,
    unsigned int* __restrict__ counts,
    float* __restrict__ csum, float* __restrict__ cmean, float* __restrict__ perp,
    float* __restrict__ out_tail, unsigned int* __restrict__ done, int q)
{
    const int rb = blockIdx.x, tid = threadIdx.x;
    const int b = rb >> 2, t0 = (rb & 3) << 6;
    const int row0 = rb * 64;                    // = b*256 + t0
    __shared__ int s_idx[64];
    __shared__ __align__(16) float qt[64][68];   // [c_local][t_local]
    __shared__ float wsum[4];
    __shared__ unsigned int lastflag;
    if (tid < 64) {
        s_idx[tid] = best_idx[row0 + tid];
        candcnt[row0 + tid] = 0u;                // reset for next layer's dist
    }
    __syncthreads();
    float cs = 0.f;
    const size_t base = (size_t)b * (NC * NT) + t0;
    const bool last = (q == NQ - 1);
    for (int ct = 0; ct < 8; ++ct) {             // c chunks of 64
        if (ct) __syncthreads();
        // gather cb[idx[r]] chunk into qt [c][t]
        #pragma unroll
        for (int i = 0; i < 4; ++i) {
            int f = tid + (i << 8);
            int r = f >> 4, cf = f & 15;
            float4 v = *(const float4*)(cb + (size_t)s_idx[r] * NC + ct * 64 + (cf << 2));
            qt[(cf << 2) + 0][r] = v.x;
            qt[(cf << 2) + 1][r] = v.y;
            qt[(cf << 2) + 2][r] = v.z;
            qt[(cf << 2) + 3][r] = v.w;
        }
        __syncthreads();
        // RMW (coalesced along t); at q=5 write qout = x - n instead of n
        #pragma unroll
        for (int i = 0; i < 4; ++i) {
            int f = tid + (i << 8);
            int c_l = f >> 4, tf = f & 15;
            size_t o = base + (size_t)(ct * 64 + c_l) * NT + (tf << 2);
            float4 r4 = *(const float4*)(src + o);
            float4 q4 = *(const float4*)&qt[c_l][tf << 2];
            float4 n;
            n.x = r4.x - q4.x; n.y = r4.y - q4.y; n.z = r4.z - q4.z; n.w = r4.w - q4.w;
            float4 ov = n;
            if (last) {
                float4 xv = *(const float4*)(x + o);
                ov.x = xv.x - n.x; ov.y = xv.y - n.y;
                ov.z = xv.z - n.z; ov.w = xv.w - n.w;
            }
            *(float4*)(dst + o) = ov;
            *(float4*)&qt[c_l][tf << 2] = n;
            cs += n.x*n.x + n.y*n.y + n.z*n.z + n.w*n.w;
        }
        __syncthreads();
        // transpose-read n and emit bf16 in (r,c) layout (skip at last layer)
        if (!last) {
            #pragma unroll
            for (int i = 0; i < 4; ++i) {
                int f = tid + (i << 8);
                int r_l = f >> 4, c4 = f & 15;
                ushort4 hh;
                hh.x = f2bf(qt[c4*4+0][r_l]); hh.y = f2bf(qt[c4*4+1][r_l]);
                hh.z = f2bf(qt[c4*4+2][r_l]); hh.w = f2bf(qt[c4*4+3][r_l]);
                *(ushort4*)(xh + (size_t)(row0 + r_l) * NC + ct * 64 + (c4 << 2)) = hh;
            }
        }
    }
    #pragma unroll
    for (int off = 32; off; off >>= 1) cs += __shfl_down(cs, off, 64);
    if ((tid & 63) == 0) wsum[tid >> 6] = cs;
    __syncthreads();
    if (tid == 0) {
        atomicAdd(&csum[q], wsum[0] + wsum[1] + wsum[2] + wsum[3]);
        __threadfence();
        lastflag = atomicAdd(done, 1u);
    }
    __syncthreads();
    if (lastflag == 255u) {                      // last block: fused per-layer stats
        float v = 0.f;
        for (int i = tid; i < NK; i += 256) {
            float p = (float)atomicAdd(&counts[i], 0u) * (1.f / (float)NROWS);
            v += p * logf(p + 1e-7f);
        }
        #pragma unroll
        for (int off = 32; off; off >>= 1) v += __shfl_down(v, off, 64);
        if ((tid & 63) == 0) wsum[tid >> 6] = v;
        __syncthreads();
        if (tid == 0) {
            float S = wsum[0] + wsum[1] + wsum[2] + wsum[3];
            perp[q]  = expf(-S);
            cmean[q] = atomicAdd(&csum[q], 0.f) * (1.f / ((float)NROWS * (float)NC));
            if (q == NQ - 1) {
                float mc = 0.f, mp = 0.f;
                for (int i = 0; i < NQ; ++i) { mc += cmean[i]; mp += perp[i]; }
                out_tail[0] = mc / (float)NQ;
                out_tail[1] = mp / (float)NQ;
            }
            *done = 0u;                          // reset for next layer
        }
    }
}

extern "C" void kernel_launch(void* const* d_in, const int* in_sizes, int n_in,
                              void* d_out, int out_size, void* d_ws, size_t ws_size,
                              hipStream_t stream) {
    const float* x  = (const float*)d_in[0];
    const float* cb = (const float*)d_in[1];       // (Q,K,C)
    float* out      = (float*)d_out;
    float* res      = out;                          // residual lives in qout slot
    float* out_idx  = out + QOUT_ELEMS;
    float* out_tail = out + QOUT_ELEMS + IDX_ELEMS;
    char* ws = (char*)d_ws;
    unsigned int* cand    = (unsigned int*)(ws + WS_CAND);
    unsigned int* candcnt = (unsigned int*)(ws + WS_CCNT);
    int*          bidx    = (int*)(ws + WS_BIDX);
    unsigned int* counts  = (unsigned int*)(ws + WS_COUNTS);
    float* csum  = (float*)(ws + WS_CSUM);
    float* cmean = (float*)(ws + WS_CMEAN);
    float* perp  = (float*)(ws + WS_PERP);
    unsigned int* done = (unsigned int*)(ws + WS_DONE);
    float* cbn   = (float*)(ws + WS_CBN);
    unsigned short* xh   = (unsigned short*)(ws + WS_XHI);
    unsigned short* cbhi = (unsigned short*)(ws + WS_CBHI);

    vq_cvt_cb<<<1536, 256, 0, stream>>>(cb, cbhi, cbn);
    vq_cvt_x<<<2048, 256, 0, stream>>>(x, xh, candcnt, done);
    for (int q = 0; q < NQ; ++q) {
        const float* src = (q == 0) ? x : res;
        const float* cbq = cb + (size_t)q * NK * NC;
        vq_dist<<<dim3(128, 4), 256, 0, stream>>>(
            xh, cbhi + (size_t)q * NK * NC, cbn + q * NK,
            cand, candcnt, counts, csum + q);
        vq_rescore<<<1024, 256, 0, stream>>>(src, cbq, cbn + q * NK, cand, candcnt,
                                             bidx, out_idx, counts, q);
        vq_update<<<256, 256, 0, stream>>>(src, x, res, cbq, bidx, xh, candcnt,
                                           counts, csum, cmean, perp, out_tail, done, q);
    }
}